// Round 2
// baseline (285.007 us; speedup 1.0000x reference)
//
#include <hip/hip_runtime.h>

typedef unsigned short u16;
typedef __attribute__((ext_vector_type(8))) short short8;
typedef __attribute__((ext_vector_type(4))) float f32x4;

#define LSTR 68   // padded leading dim for LDS tiles (breaks bank conflicts)

__device__ __forceinline__ u16 f2bf(float f){
  union { float f; unsigned int i; } v; v.f = f;
  unsigned int x = v.i;
  return (u16)((x + 0x7FFFu + ((x >> 16) & 1u)) >> 16);   // RNE
}

// convert 8 contiguous f32 to a bf16 MFMA fragment
__device__ __forceinline__ short8 cvt8(const float* __restrict__ p){
  float4 a = *(const float4*)p;
  float4 b = *(const float4*)(p + 4);
  short8 r;
  r[0]=(short)f2bf(a.x); r[1]=(short)f2bf(a.y); r[2]=(short)f2bf(a.z); r[3]=(short)f2bf(a.w);
  r[4]=(short)f2bf(b.x); r[5]=(short)f2bf(b.y); r[6]=(short)f2bf(b.z); r[7]=(short)f2bf(b.w);
  return r;
}

// ---------------------------------------------------------------------------
// LN of the 128 active rows (b in [0,8), s in [0,16)) with lna and lnb weights.
// f32 in, bf16 out (MFMA A-operand staging).
// ---------------------------------------------------------------------------
__global__ __launch_bounds__(256) void k_ln(const float* __restrict__ x,
    const float* __restrict__ lna, const float* __restrict__ lnb,
    u16* __restrict__ xa, u16* __restrict__ xb)
{
  __shared__ float ssum[4], ssq[4];
  int row = blockIdx.x;          // 0..127 = b*16+s
  int b = row >> 4, s = row & 15;
  int tid = threadIdx.x;
  const float* xr = x + ((size_t)b*4096 + s)*1024;
  float4 v = *(const float4*)(xr + tid*4);
  float sum = v.x+v.y+v.z+v.w;
  float sq  = v.x*v.x+v.y*v.y+v.z*v.z+v.w*v.w;
  #pragma unroll
  for (int o=32;o>0;o>>=1){ sum += __shfl_xor(sum,o); sq += __shfl_xor(sq,o); }
  int w = tid>>6;
  if ((tid&63)==0){ ssum[w]=sum; ssq[w]=sq; }
  __syncthreads();
  sum = ssum[0]+ssum[1]+ssum[2]+ssum[3];
  sq  = ssq[0]+ssq[1]+ssq[2]+ssq[3];
  float m   = sum * (1.f/1024.f);
  float var = sq  * (1.f/1024.f) - m*m;          // biased variance, torch-style
  float rs  = rsqrtf(fmaxf(var, 0.f) + 1e-5f);
  float4 wa = *(const float4*)(lna + tid*4);
  float4 wb = *(const float4*)(lnb + tid*4);
  float n0=(v.x-m)*rs, n1=(v.y-m)*rs, n2=(v.z-m)*rs, n3=(v.w-m)*rs;
  ushort4 oa, obv;
  oa.x=f2bf(n0*wa.x); oa.y=f2bf(n1*wa.y); oa.z=f2bf(n2*wa.z); oa.w=f2bf(n3*wa.w);
  obv.x=f2bf(n0*wb.x); obv.y=f2bf(n1*wb.y); obv.z=f2bf(n2*wb.z); obv.w=f2bf(n3*wb.w);
  *(ushort4*)(xa + (size_t)row*1024 + tid*4) = oa;
  *(ushort4*)(xb + (size_t)row*1024 + tid*4) = obv;
}

// ---------------------------------------------------------------------------
// q/k/v projection: qkv[128,3072] = [xa|xb] @ {qw,kw,vw}^T (+bias), f32 out.
// MFMA 16x16x32 bf16; A from ws (bf16), W converted f32->bf16 inline.
// tiles = 8 mtiles * (3 mats * 64 ntiles) = 1536; 4 waves/block -> 384 blocks.
// ---------------------------------------------------------------------------
__global__ __launch_bounds__(256) void k_proj(const u16* __restrict__ xa, const u16* __restrict__ xb,
    const float* __restrict__ qw, const float* __restrict__ qb,
    const float* __restrict__ kw, const float* __restrict__ vw, const float* __restrict__ vb,
    float* __restrict__ qkv)
{
  int tid = threadIdx.x, wave = tid>>6, lane = tid&63;
  int tile = blockIdx.x*4 + wave;       // 0..1535
  int mt = tile / 192, nt = tile % 192;
  int mat = nt >> 6, nct = nt & 63;
  const u16*   A = (mat==0) ? xa : xb;
  const float* W = (mat==0) ? qw : ((mat==1) ? kw : vw);
  int m_lane = lane & 15, quad = lane >> 4;
  const u16*   ap = A + (size_t)(mt*16  + m_lane)*1024 + quad*8;
  const float* bp = W + (size_t)(nct*16 + m_lane)*1024 + quad*8;
  f32x4 acc = {0.f,0.f,0.f,0.f};
  #pragma unroll 4
  for (int k0=0;k0<1024;k0+=32){
    short8 af = *(const short8*)(ap + k0);
    short8 bf = cvt8(bp + k0);
    acc = __builtin_amdgcn_mfma_f32_16x16x32_bf16(af, bf, acc, 0, 0, 0);
  }
  int n = nct*16 + m_lane;
  float bias = 0.f;
  if (mat==0) bias = qb[n];             // k linear has bias=False
  else if (mat==2) bias = vb[n];
  float* outp = qkv + (size_t)mat*131072;
  #pragma unroll
  for (int i=0;i<4;i++){
    int row = mt*16 + quad*4 + i;       // C/D: col=lane&15, row=quad*4+reg
    outp[(size_t)row*1024 + n] = acc[i] + bias;
  }
}

// ---------------------------------------------------------------------------
// Per-(b,h) attention, all f32: kn/vi once, then (deterministically 2-iter)
// A0=step(q), qcur=q+A0, A1=step(qcur). 128 blocks x 256 threads;
// thread = (row r=tid>>4, col group cg=tid&15 -> 4 cols).
// ---------------------------------------------------------------------------
__device__ __forceinline__ void mm4(const float* __restrict__ X, const float* __restrict__ W,
                                    const float* __restrict__ bias, int r, int cg, float out4[4])
{
  const float* xrow = X + r*LSTR;
  #pragma unroll
  for (int i=0;i<4;i++){
    int o = cg*4+i;
    const float* wrow = W + o*LSTR;
    float acc = bias[o];
    #pragma unroll
    for (int d=0; d<64; d+=4){
      float4 w4 = *(const float4*)(wrow + d);
      float4 x4 = *(const float4*)(xrow + d);
      acc += x4.x*w4.x + x4.y*w4.y + x4.z*w4.z + x4.w*w4.w;
    }
    out4[i] = acc;
  }
}

__device__ __forceinline__ void ln4(float v[4], const float* __restrict__ lnw, int cg)
{
  float s = v[0]+v[1]+v[2]+v[3];
  float q = v[0]*v[0]+v[1]*v[1]+v[2]*v[2]+v[3]*v[3];
  #pragma unroll
  for (int m=1;m<16;m<<=1){ s += __shfl_xor(s,m); q += __shfl_xor(q,m); }
  float mn  = s * (1.f/64.f);
  float var = q * (1.f/64.f) - mn*mn;
  float rs  = rsqrtf(fmaxf(var,0.f) + 1e-5f);
  #pragma unroll
  for (int i=0;i<4;i++) v[i] = (v[i]-mn)*rs*lnw[cg*4+i];
}

__device__ __forceinline__ void attn_iter(const float* __restrict__ qsrc,
    const float* __restrict__ wq, const float* __restrict__ lqb, const float* __restrict__ lnc,
    float* __restrict__ qns, float* __restrict__ ps,
    const float* __restrict__ kks, const float* __restrict__ vis,
    int r, int cg, float a4[4])
{
  int c0 = cg*4;
  float qn4[4];
  mm4(qsrc, wq, lqb, r, cg, qn4);
  ln4(qn4, lnc, cg);
  #pragma unroll
  for (int i=0;i<4;i++) qns[r*LSTR+c0+i] = qn4[i];
  __syncthreads();
  // scores: this thread computes S[r][cg]
  float acc = 0.f;
  #pragma unroll
  for (int d=0;d<64;d+=4){
    float4 a = *(const float4*)(qns + r*LSTR + d);
    float4 b = *(const float4*)(kks + cg*LSTR + d);
    acc += a.x*b.x + a.y*b.y + a.z*b.z + a.w*b.w;
  }
  acc *= 0.125f;                         // 1/sqrt(64)
  float mx = acc;
  #pragma unroll
  for (int m=1;m<16;m<<=1) mx = fmaxf(mx, __shfl_xor(mx,m));
  float e = __expf(acc - mx);
  float sm = e;
  #pragma unroll
  for (int m=1;m<16;m<<=1) sm += __shfl_xor(sm,m);
  ps[r*17+cg] = e / sm;
  __syncthreads();
  #pragma unroll
  for (int i=0;i<4;i++){
    int o = c0+i; float s = 0.f;
    #pragma unroll
    for (int c=0;c<16;c++) s += ps[r*17+c]*vis[c*LSTR+o];
    a4[i] = s;
  }
}

__global__ __launch_bounds__(256) void k_attn(const float* __restrict__ qkv,
    const float* __restrict__ lnc, const float* __restrict__ lnd,
    const float* __restrict__ lqw, const float* __restrict__ lqb,
    const float* __restrict__ lkw, const float* __restrict__ lkb,
    const float* __restrict__ lvw, const float* __restrict__ lvb,
    u16* __restrict__ attn)
{
  __shared__ float qs[16*LSTR], ks[16*LSTR], vs[16*LSTR];
  __shared__ float kks[16*LSTR], vis[16*LSTR], qns[16*LSTR], qcs[16*LSTR];
  __shared__ float ps[16*17];
  __shared__ float wq[64*LSTR], wk[64*LSTR], wv[64*LSTR];
  __shared__ float sb[5*64];   // lqb, lkb, lvb, lnc, lnd

  int tid = threadIdx.x, bh = blockIdx.x;
  int b = bh>>4, h = bh&15;
  int r = tid>>4, cg = tid&15, c0 = cg*4;

  // stage 64x64 weights and biases/ln-weights (all f32)
  for (int i = tid; i < 1024; i += 256){
    int o = i >> 4, d = (i & 15)*4;
    *(float4*)(wq + o*LSTR + d) = *(const float4*)(lqw + i*4);
    *(float4*)(wk + o*LSTR + d) = *(const float4*)(lkw + i*4);
    *(float4*)(wv + o*LSTR + d) = *(const float4*)(lvw + i*4);
  }
  if (tid < 64){
    sb[tid]       = lqb[tid];
    sb[64  + tid] = lkb[tid];
    sb[128 + tid] = lvb[tid];
    sb[192 + tid] = lnc[tid];
    sb[256 + tid] = lnd[tid];
  }
  // stage q,k,v 16x64 tiles (f32)
  size_t base = (size_t)(b*16 + r)*1024 + h*64 + c0;
  float4 fq = *(const float4*)(qkv + base);
  float4 fk = *(const float4*)(qkv + 131072 + base);
  float4 fv = *(const float4*)(qkv + 262144 + base);
  float q4[4] = {fq.x, fq.y, fq.z, fq.w};
  #pragma unroll
  for (int i=0;i<4;i++) qs[r*LSTR+c0+i] = q4[i];
  *(float4*)(ks + r*LSTR + c0) = fk;
  *(float4*)(vs + r*LSTR + c0) = fv;
  __syncthreads();

  // kn = LN_d(k @ lkw^T + lkb),  vi = v @ lvw^T + lvb   (iteration-invariant)
  float kk4[4]; mm4(ks, wk, sb+64, r, cg, kk4); ln4(kk4, sb+256, cg);
  float vi4[4]; mm4(vs, wv, sb+128, r, cg, vi4);
  #pragma unroll
  for (int i=0;i<4;i++){ kks[r*LSTR+c0+i] = kk4[i]; vis[r*LSTR+c0+i] = vi4[i]; }
  __syncthreads();

  float a4[4];
  attn_iter(qs, wq, sb+0, sb+192, qns, ps, kks, vis, r, cg, a4);   // iter 0
  #pragma unroll
  for (int i=0;i<4;i++) qcs[r*LSTR+c0+i] = q4[i] + a4[i];          // qcur = q + A0
  __syncthreads();
  attn_iter(qcs, wq, sb+0, sb+192, qns, ps, kks, vis, r, cg, a4);  // iter 1 (break fires)

  ushort4 ov;
  ov.x=f2bf(a4[0]); ov.y=f2bf(a4[1]); ov.z=f2bf(a4[2]); ov.w=f2bf(a4[3]);
  *(ushort4*)(attn + (size_t)(b*16 + r)*1024 + h*64 + c0) = ov;
}

// ---------------------------------------------------------------------------
// Fill entire output with ob (rows s>=16 are exactly ob; s<16 overwritten later)
// 32768 blocks * 256 thr * 4 f32 = 33,554,432 exactly.
// ---------------------------------------------------------------------------
__global__ __launch_bounds__(256) void k_fill(const float* __restrict__ ob, float* __restrict__ out)
{
  size_t idx = ((size_t)blockIdx.x*256 + threadIdx.x)*4;
  int o = (int)(idx & 1023);
  *(float4*)(out + idx) = *(const float4*)(ob + o);
}

// ---------------------------------------------------------------------------
// Output projection for the 128 active rows: out[b,s,:] = attn_row @ ow^T + ob
// MFMA, tiles = 8 mtiles * 64 ntiles = 512 waves -> 128 blocks. f32 out.
// ---------------------------------------------------------------------------
__global__ __launch_bounds__(256) void k_oproj(const u16* __restrict__ attn,
    const float* __restrict__ ow, const float* __restrict__ ob, float* __restrict__ out)
{
  int tid = threadIdx.x, wave = tid>>6, lane = tid&63;
  int tile = blockIdx.x*4 + wave;       // 0..511
  int mt = tile >> 6, nt = tile & 63;
  int m_lane = lane & 15, quad = lane >> 4;
  const u16*   ap = attn + (size_t)(mt*16 + m_lane)*1024 + quad*8;
  const float* bp = ow   + (size_t)(nt*16 + m_lane)*1024 + quad*8;
  f32x4 acc = {0.f,0.f,0.f,0.f};
  #pragma unroll 4
  for (int k0=0;k0<1024;k0+=32){
    short8 af = *(const short8*)(ap + k0);
    short8 bf = cvt8(bp + k0);
    acc = __builtin_amdgcn_mfma_f32_16x16x32_bf16(af, bf, acc, 0, 0, 0);
  }
  int n = nt*16 + m_lane;
  float bias = ob[n];
  #pragma unroll
  for (int i=0;i<4;i++){
    int s = quad*4 + i;                 // tile-local row = seq pos (mt = batch)
    out[((size_t)mt*4096 + s)*1024 + n] = acc[i] + bias;
  }
}

// ---------------------------------------------------------------------------
extern "C" void kernel_launch(void* const* d_in, const int* in_sizes, int n_in,
                              void* d_out, int out_size, void* d_ws, size_t ws_size,
                              hipStream_t stream)
{
  const float* x    = (const float*)d_in[0];
  const float* qw   = (const float*)d_in[1];
  const float* qb   = (const float*)d_in[2];
  const float* kw   = (const float*)d_in[3];
  const float* vw   = (const float*)d_in[4];
  const float* vb   = (const float*)d_in[5];
  const float* ow   = (const float*)d_in[6];
  const float* ob   = (const float*)d_in[7];
  const float* lna  = (const float*)d_in[8];
  const float* lnb  = (const float*)d_in[9];
  const float* lnc  = (const float*)d_in[10];
  const float* lnd  = (const float*)d_in[11];
  const float* lqw  = (const float*)d_in[12];
  const float* lqb  = (const float*)d_in[13];
  const float* lkw  = (const float*)d_in[14];
  const float* lkb  = (const float*)d_in[15];
  const float* lvw  = (const float*)d_in[16];
  const float* lvb  = (const float*)d_in[17];

  char* ws = (char*)d_ws;
  u16*   xa   = (u16*)(ws);                        // 128*1024 bf16
  u16*   xb   = (u16*)(ws + 262144);               // 128*1024 bf16
  float* qkv  = (float*)(ws + 524288);             // 3*128*1024 f32
  u16*   attn = (u16*)(ws + 2097152);              // 128*1024 bf16
  float* out  = (float*)d_out;

  k_ln   <<<  128, 256, 0, stream>>>(x, lna, lnb, xa, xb);
  k_proj <<<  384, 256, 0, stream>>>(xa, xb, qw, qb, kw, vw, vb, qkv);
  k_attn <<<  128, 256, 0, stream>>>(qkv, lnc, lnd, lqw, lqb, lkw, lkb, lvw, lvb, attn);
  k_fill <<<32768, 256, 0, stream>>>(ob, out);
  k_oproj<<<  128, 256, 0, stream>>>(attn, ow, ob, out);
}

// Round 3
// 283.475 us; speedup vs baseline: 1.0054x; 1.0054x over previous
//
#include <hip/hip_runtime.h>

typedef unsigned short u16;
typedef __attribute__((ext_vector_type(8))) short short8;
typedef __attribute__((ext_vector_type(4))) float f32x4;

#define LSTR 68     // padded leading dim for f32 LDS tiles in k_attn
#define ASTR 1032   // padded bf16 leading dim (1024+8): 16B-aligned rows, 2-way-max bank conflict

__device__ __forceinline__ u16 f2bf(float f){
  union { float f; unsigned int i; } v; v.f = f;
  unsigned int x = v.i;
  return (u16)((x + 0x7FFFu + ((x >> 16) & 1u)) >> 16);   // RNE
}

// convert 8 contiguous f32 to a bf16 MFMA fragment
__device__ __forceinline__ short8 cvt8(const float* __restrict__ p){
  float4 a = *(const float4*)p;
  float4 b = *(const float4*)(p + 4);
  short8 r;
  r[0]=(short)f2bf(a.x); r[1]=(short)f2bf(a.y); r[2]=(short)f2bf(a.z); r[3]=(short)f2bf(a.w);
  r[4]=(short)f2bf(b.x); r[5]=(short)f2bf(b.y); r[6]=(short)f2bf(b.z); r[7]=(short)f2bf(b.w);
  return r;
}

// ---------------------------------------------------------------------------
// Fused LN + q/k/v projection.
// 384 blocks, 48 blocks per mtile (mt = batch, rows s=0..15). Each block
// recomputes LN of its 16x1024 tile into LDS (bf16, both lna- and lnb-scaled),
// then 4 waves do MFMA 16x16x32 tiles of qkv[128,3072] = A @ {qw,kw,vw}^T.
// ---------------------------------------------------------------------------
__global__ __launch_bounds__(256) void k_lnproj(const float* __restrict__ x,
    const float* __restrict__ lna, const float* __restrict__ lnb,
    const float* __restrict__ qw, const float* __restrict__ qb,
    const float* __restrict__ kw, const float* __restrict__ vw,
    const float* __restrict__ vb, float* __restrict__ qkv)
{
  __shared__ u16 Aa[16*ASTR];   // LN_a(x) rows (q-path)
  __shared__ u16 Ab[16*ASTR];   // LN_b(x) rows (k/v-path)

  int tid = threadIdx.x, wave = tid>>6, lane = tid&63;
  int blk = blockIdx.x;          // 0..383
  int mt  = blk / 48;            // 0..7 (= batch; rows are s=0..15)

  // ---- LN stage: 16 threads per row, 64 elems (16 float4) each ----
  int r = tid >> 4, l16 = tid & 15;
  const float* xr = x + ((size_t)mt*4096 + r)*1024;
  float4 vv[16];
  float sum = 0.f, sq = 0.f;
  #pragma unroll
  for (int j=0;j<16;j++){
    vv[j] = *(const float4*)(xr + (j*16 + l16)*4);
    sum += vv[j].x+vv[j].y+vv[j].z+vv[j].w;
    sq  += vv[j].x*vv[j].x + vv[j].y*vv[j].y + vv[j].z*vv[j].z + vv[j].w*vv[j].w;
  }
  #pragma unroll
  for (int m=1;m<16;m<<=1){ sum += __shfl_xor(sum,m); sq += __shfl_xor(sq,m); }
  float mn  = sum * (1.f/1024.f);
  float var = sq  * (1.f/1024.f) - mn*mn;          // biased variance, torch-style
  float rs  = rsqrtf(fmaxf(var, 0.f) + 1e-5f);
  #pragma unroll
  for (int j=0;j<16;j++){
    int c = (j*16 + l16)*4;
    float4 wa = *(const float4*)(lna + c);
    float4 wb = *(const float4*)(lnb + c);
    float n0=(vv[j].x-mn)*rs, n1=(vv[j].y-mn)*rs, n2=(vv[j].z-mn)*rs, n3=(vv[j].w-mn)*rs;
    ushort4 oa, obv;
    oa.x =f2bf(n0*wa.x); oa.y =f2bf(n1*wa.y); oa.z =f2bf(n2*wa.z); oa.w =f2bf(n3*wa.w);
    obv.x=f2bf(n0*wb.x); obv.y=f2bf(n1*wb.y); obv.z=f2bf(n2*wb.z); obv.w=f2bf(n3*wb.w);
    *(ushort4*)(Aa + r*ASTR + c) = oa;
    *(ushort4*)(Ab + r*ASTR + c) = obv;
  }
  __syncthreads();

  // ---- MFMA stage ----
  int tile = blk*4 + wave;             // tile/192 == mt by construction
  int nt = tile % 192, mat = nt >> 6, nct = nt & 63;
  const u16*   Al = (mat==0) ? Aa : Ab;
  const float* W  = (mat==0) ? qw : ((mat==1) ? kw : vw);
  int m_lane = lane & 15, quad = lane >> 4;
  const u16*   ap = Al + m_lane*ASTR + quad*8;
  const float* bp = W + (size_t)(nct*16 + m_lane)*1024 + quad*8;
  f32x4 acc = {0.f,0.f,0.f,0.f};
  #pragma unroll 4
  for (int k0=0;k0<1024;k0+=32){
    short8 af = *(const short8*)(ap + k0);
    short8 bf = cvt8(bp + k0);
    acc = __builtin_amdgcn_mfma_f32_16x16x32_bf16(af, bf, acc, 0, 0, 0);
  }
  int n = nct*16 + m_lane;
  float bias = 0.f;
  if (mat==0) bias = qb[n];            // k linear has bias=False
  else if (mat==2) bias = vb[n];
  float* outp = qkv + (size_t)mat*131072;
  #pragma unroll
  for (int i=0;i<4;i++){
    int row = mt*16 + quad*4 + i;      // C/D: col=lane&15, row=quad*4+reg
    outp[(size_t)row*1024 + n] = acc[i] + bias;
  }
}

// ---------------------------------------------------------------------------
// Per-(b,h) attention, all f32: kn/vi once, then (deterministically 2-iter)
// A0=step(q), qcur=q+A0, A1=step(qcur). 128 blocks x 256 threads;
// thread = (row r=tid>>4, col group cg=tid&15 -> 4 cols).
// ---------------------------------------------------------------------------
__device__ __forceinline__ void mm4(const float* __restrict__ X, const float* __restrict__ W,
                                    const float* __restrict__ bias, int r, int cg, float out4[4])
{
  const float* xrow = X + r*LSTR;
  #pragma unroll
  for (int i=0;i<4;i++){
    int o = cg*4+i;
    const float* wrow = W + o*LSTR;
    float acc = bias[o];
    #pragma unroll
    for (int d=0; d<64; d+=4){
      float4 w4 = *(const float4*)(wrow + d);
      float4 x4 = *(const float4*)(xrow + d);
      acc += x4.x*w4.x + x4.y*w4.y + x4.z*w4.z + x4.w*w4.w;
    }
    out4[i] = acc;
  }
}

__device__ __forceinline__ void ln4(float v[4], const float* __restrict__ lnw, int cg)
{
  float s = v[0]+v[1]+v[2]+v[3];
  float q = v[0]*v[0]+v[1]*v[1]+v[2]*v[2]+v[3]*v[3];
  #pragma unroll
  for (int m=1;m<16;m<<=1){ s += __shfl_xor(s,m); q += __shfl_xor(q,m); }
  float mn  = s * (1.f/64.f);
  float var = q * (1.f/64.f) - mn*mn;
  float rs  = rsqrtf(fmaxf(var,0.f) + 1e-5f);
  #pragma unroll
  for (int i=0;i<4;i++) v[i] = (v[i]-mn)*rs*lnw[cg*4+i];
}

__device__ __forceinline__ void attn_iter(const float* __restrict__ qsrc,
    const float* __restrict__ wq, const float* __restrict__ lqb, const float* __restrict__ lnc,
    float* __restrict__ qns, float* __restrict__ ps,
    const float* __restrict__ kks, const float* __restrict__ vis,
    int r, int cg, float a4[4])
{
  int c0 = cg*4;
  float qn4[4];
  mm4(qsrc, wq, lqb, r, cg, qn4);
  ln4(qn4, lnc, cg);
  #pragma unroll
  for (int i=0;i<4;i++) qns[r*LSTR+c0+i] = qn4[i];
  __syncthreads();
  // scores: this thread computes S[r][cg]
  float acc = 0.f;
  #pragma unroll
  for (int d=0;d<64;d+=4){
    float4 a = *(const float4*)(qns + r*LSTR + d);
    float4 b = *(const float4*)(kks + cg*LSTR + d);
    acc += a.x*b.x + a.y*b.y + a.z*b.z + a.w*b.w;
  }
  acc *= 0.125f;                         // 1/sqrt(64)
  float mx = acc;
  #pragma unroll
  for (int m=1;m<16;m<<=1) mx = fmaxf(mx, __shfl_xor(mx,m));
  float e = __expf(acc - mx);
  float sm = e;
  #pragma unroll
  for (int m=1;m<16;m<<=1) sm += __shfl_xor(sm,m);
  ps[r*17+cg] = e / sm;
  __syncthreads();
  #pragma unroll
  for (int i=0;i<4;i++){
    int o = c0+i; float s = 0.f;
    #pragma unroll
    for (int c=0;c<16;c++) s += ps[r*17+c]*vis[c*LSTR+o];
    a4[i] = s;
  }
}

__global__ __launch_bounds__(256) void k_attn(const float* __restrict__ qkv,
    const float* __restrict__ lnc, const float* __restrict__ lnd,
    const float* __restrict__ lqw, const float* __restrict__ lqb,
    const float* __restrict__ lkw, const float* __restrict__ lkb,
    const float* __restrict__ lvw, const float* __restrict__ lvb,
    u16* __restrict__ attn)
{
  __shared__ float qs[16*LSTR], ks[16*LSTR], vs[16*LSTR];
  __shared__ float kks[16*LSTR], vis[16*LSTR], qns[16*LSTR], qcs[16*LSTR];
  __shared__ float ps[16*17];
  __shared__ float wq[64*LSTR], wk[64*LSTR], wv[64*LSTR];
  __shared__ float sb[5*64];   // lqb, lkb, lvb, lnc, lnd

  int tid = threadIdx.x, bh = blockIdx.x;
  int b = bh>>4, h = bh&15;
  int r = tid>>4, cg = tid&15, c0 = cg*4;

  // stage 64x64 weights and biases/ln-weights (all f32)
  for (int i = tid; i < 1024; i += 256){
    int o = i >> 4, d = (i & 15)*4;
    *(float4*)(wq + o*LSTR + d) = *(const float4*)(lqw + i*4);
    *(float4*)(wk + o*LSTR + d) = *(const float4*)(lkw + i*4);
    *(float4*)(wv + o*LSTR + d) = *(const float4*)(lvw + i*4);
  }
  if (tid < 64){
    sb[tid]       = lqb[tid];
    sb[64  + tid] = lkb[tid];
    sb[128 + tid] = lvb[tid];
    sb[192 + tid] = lnc[tid];
    sb[256 + tid] = lnd[tid];
  }
  // stage q,k,v 16x64 tiles (f32)
  size_t base = (size_t)(b*16 + r)*1024 + h*64 + c0;
  float4 fq = *(const float4*)(qkv + base);
  float4 fk = *(const float4*)(qkv + 131072 + base);
  float4 fv = *(const float4*)(qkv + 262144 + base);
  float q4[4] = {fq.x, fq.y, fq.z, fq.w};
  #pragma unroll
  for (int i=0;i<4;i++) qs[r*LSTR+c0+i] = q4[i];
  *(float4*)(ks + r*LSTR + c0) = fk;
  *(float4*)(vs + r*LSTR + c0) = fv;
  __syncthreads();

  // kn = LN_d(k @ lkw^T + lkb),  vi = v @ lvw^T + lvb   (iteration-invariant)
  float kk4[4]; mm4(ks, wk, sb+64, r, cg, kk4); ln4(kk4, sb+256, cg);
  float vi4[4]; mm4(vs, wv, sb+128, r, cg, vi4);
  #pragma unroll
  for (int i=0;i<4;i++){ kks[r*LSTR+c0+i] = kk4[i]; vis[r*LSTR+c0+i] = vi4[i]; }
  __syncthreads();

  float a4[4];
  attn_iter(qs, wq, sb+0, sb+192, qns, ps, kks, vis, r, cg, a4);   // iter 0
  #pragma unroll
  for (int i=0;i<4;i++) qcs[r*LSTR+c0+i] = q4[i] + a4[i];          // qcur = q + A0
  __syncthreads();
  attn_iter(qcs, wq, sb+0, sb+192, qns, ps, kks, vis, r, cg, a4);  // iter 1 (break fires)

  ushort4 ov;
  ov.x=f2bf(a4[0]); ov.y=f2bf(a4[1]); ov.z=f2bf(a4[2]); ov.w=f2bf(a4[3]);
  *(ushort4*)(attn + (size_t)(b*16 + r)*1024 + h*64 + c0) = ov;
}

// ---------------------------------------------------------------------------
// Fused output fill + output projection.
// Blocks 0..32767: one (b,s) row each; write ob broadcast, SKIPPING the 128
// active rows (s<16) to avoid racing the oproj blocks.
// Blocks 32768..32895: MFMA oproj of the 128 active rows (512 tile-waves):
// out[b,s,:] = attn_row @ ow^T + ob.
// ---------------------------------------------------------------------------
__global__ __launch_bounds__(256) void k_fillproj(const u16* __restrict__ attn,
    const float* __restrict__ ow, const float* __restrict__ ob, float* __restrict__ out)
{
  int tid = threadIdx.x;
  if (blockIdx.x < 32768){
    int row = blockIdx.x;                // row = b*4096 + s
    if ((row & 4095) < 16) return;       // active rows handled by oproj blocks
    *(float4*)(out + (size_t)row*1024 + tid*4) = *(const float4*)(ob + tid*4);
    return;
  }
  int wave = tid>>6, lane = tid&63;
  int tile = (blockIdx.x - 32768)*4 + wave;   // 0..511
  int mt = tile >> 6, nt = tile & 63;
  int m_lane = lane & 15, quad = lane >> 4;
  const u16*   ap = attn + (size_t)(mt*16 + m_lane)*1024 + quad*8;
  const float* bp = ow   + (size_t)(nt*16 + m_lane)*1024 + quad*8;
  f32x4 acc = {0.f,0.f,0.f,0.f};
  #pragma unroll 4
  for (int k0=0;k0<1024;k0+=32){
    short8 af = *(const short8*)(ap + k0);
    short8 bf = cvt8(bp + k0);
    acc = __builtin_amdgcn_mfma_f32_16x16x32_bf16(af, bf, acc, 0, 0, 0);
  }
  int n = nt*16 + m_lane;
  float bias = ob[n];
  #pragma unroll
  for (int i=0;i<4;i++){
    int s = quad*4 + i;                  // tile-local row = seq pos (mt = batch)
    out[((size_t)mt*4096 + s)*1024 + n] = acc[i] + bias;
  }
}

// ---------------------------------------------------------------------------
extern "C" void kernel_launch(void* const* d_in, const int* in_sizes, int n_in,
                              void* d_out, int out_size, void* d_ws, size_t ws_size,
                              hipStream_t stream)
{
  const float* x    = (const float*)d_in[0];
  const float* qw   = (const float*)d_in[1];
  const float* qb   = (const float*)d_in[2];
  const float* kw   = (const float*)d_in[3];
  const float* vw   = (const float*)d_in[4];
  const float* vb   = (const float*)d_in[5];
  const float* ow   = (const float*)d_in[6];
  const float* ob   = (const float*)d_in[7];
  const float* lna  = (const float*)d_in[8];
  const float* lnb  = (const float*)d_in[9];
  const float* lnc  = (const float*)d_in[10];
  const float* lnd  = (const float*)d_in[11];
  const float* lqw  = (const float*)d_in[12];
  const float* lqb  = (const float*)d_in[13];
  const float* lkw  = (const float*)d_in[14];
  const float* lkb  = (const float*)d_in[15];
  const float* lvw  = (const float*)d_in[16];
  const float* lvb  = (const float*)d_in[17];

  char* ws = (char*)d_ws;
  float* qkv  = (float*)(ws);              // 3*128*1024 f32 = 1.5 MiB
  u16*   attn = (u16*)(ws + 1572864);      // 128*1024 bf16 = 256 KiB
  float* out  = (float*)d_out;

  k_lnproj  <<<  384, 256, 0, stream>>>(x, lna, lnb, qw, qb, kw, vw, vb, qkv);
  k_attn    <<<  128, 256, 0, stream>>>(qkv, lnc, lnd, lqw, lqb, lkw, lkb, lvw, lvb, attn);
  k_fillproj<<<32896, 256, 0, stream>>>(attn, ow, ob, out);
}